// Round 3
// baseline (506.596 us; speedup 1.0000x reference)
//
#include <hip/hip_runtime.h>
#include <math.h>

#define D_DIM 256
#define K_NUM 4096
#define N_ROWS 32768
#define QCAP 640
#define MARGIN 0.02f

typedef _Float16 half8 __attribute__((ext_vector_type(8)));
typedef float floatx4 __attribute__((ext_vector_type(4)));

// ---------------- vv[k] = sum_d V[d][k]^2 (unchanged, passed r1/r2) ----------
__global__ __launch_bounds__(256) void vq_vv(const float* __restrict__ V,
                                             float* __restrict__ vv) {
  int k = blockIdx.x * 256 + threadIdx.x;
  float acc = 0.0f;
  for (int d = 0; d < D_DIM; ++d) {
    float v = V[(size_t)d * K_NUM + k];
    acc = __fadd_rn(acc, __fmul_rn(v, v));
  }
  vv[k] = acc;
}

// numpy pairwise sum-of-squares over 128 floats (unchanged, passed r1/r2)
__device__ inline float np_pw128_sumsq(const float* __restrict__ p) {
  float r[8];
  float4 a = *(const float4*)p, b = *(const float4*)(p + 4);
  r[0] = __fmul_rn(a.x, a.x); r[1] = __fmul_rn(a.y, a.y);
  r[2] = __fmul_rn(a.z, a.z); r[3] = __fmul_rn(a.w, a.w);
  r[4] = __fmul_rn(b.x, b.x); r[5] = __fmul_rn(b.y, b.y);
  r[6] = __fmul_rn(b.z, b.z); r[7] = __fmul_rn(b.w, b.w);
#pragma unroll
  for (int i = 8; i < 128; i += 8) {
    a = *(const float4*)(p + i); b = *(const float4*)(p + i + 4);
    r[0] = __fadd_rn(r[0], __fmul_rn(a.x, a.x));
    r[1] = __fadd_rn(r[1], __fmul_rn(a.y, a.y));
    r[2] = __fadd_rn(r[2], __fmul_rn(a.z, a.z));
    r[3] = __fadd_rn(r[3], __fmul_rn(a.w, a.w));
    r[4] = __fadd_rn(r[4], __fmul_rn(b.x, b.x));
    r[5] = __fadd_rn(r[5], __fmul_rn(b.y, b.y));
    r[6] = __fadd_rn(r[6], __fmul_rn(b.z, b.z));
    r[7] = __fadd_rn(r[7], __fmul_rn(b.w, b.w));
  }
  float t01 = __fadd_rn(r[0], r[1]);
  float t23 = __fadd_rn(r[2], r[3]);
  float t45 = __fadd_rn(r[4], r[5]);
  float t67 = __fadd_rn(r[6], r[7]);
  return __fadd_rn(__fadd_rn(t01, t23), __fadd_rn(t45, t67));
}

__global__ __launch_bounds__(256) void vq_xx(const float* __restrict__ X,
                                             float* __restrict__ xx) {
  int n = blockIdx.x * 256 + threadIdx.x;
  const float* p = X + (size_t)n * D_DIM;
  xx[n] = __fadd_rn(np_pw128_sumsq(p), np_pw128_sumsq(p + 128));
}

// ---- V [256][4096] -> vtb f16 [dc 0..31][col][8] AND vt f32 [4096][256] -----
__global__ __launch_bounds__(256) void vq_prep(const float* __restrict__ V,
                                               _Float16* __restrict__ vtb,
                                               float* __restrict__ vt,
                                               int write_vt) {
  __shared__ float tile[256][64];   // 64 KB
  const int col0 = blockIdx.x * 64;
  const int cq = threadIdx.x >> 6;  // 0..3
  const int cl = threadIdx.x & 63;
#pragma unroll
  for (int it = 0; it < 64; ++it) {
    int d = it * 4 + cq;
    tile[d][cl] = V[(size_t)d * K_NUM + col0 + cl];
  }
  __syncthreads();
#pragma unroll
  for (int q = 0; q < 8; ++q) {
    int dc = q * 4 + cq;            // 0..31
    half8 h;
#pragma unroll
    for (int j = 0; j < 8; ++j) h[j] = (_Float16)tile[dc * 8 + j][cl];
    *(half8*)(vtb + ((size_t)dc * K_NUM + col0 + cl) * 8) = h;
  }
  if (write_vt) {
#pragma unroll
    for (int j = 0; j < 16; ++j) {
      int d0 = cq * 64 + j * 4;
      float4 f;
      f.x = tile[d0 + 0][cl]; f.y = tile[d0 + 1][cl];
      f.z = tile[d0 + 2][cl]; f.w = tile[d0 + 3][cl];
      *(float4*)(vt + (size_t)(col0 + cl) * D_DIM + d0) = f;
    }
  }
}

// ---------------- fp16 MFMA screen (128-row blocks, rf=8) --------------------
struct alignas(16) ScreenShared {
  _Float16 a[128 * 256];   // 64 KB, XOR-swizzled
  float vvs[K_NUM];        // 16 KB
  float xxs[128];
  float wmin[8][128];      // 4 KB
  float thr[128];
  unsigned qbuf[QCAP];
  float qscore[QCAP];
  int qn;
};

__device__ __forceinline__ void vq_push(ScreenShared& sh, int r, int col) {
  int u = atomicAdd(&sh.qn, 1);
  if (u < QCAP) sh.qbuf[u] = ((unsigned)r << 12) | (unsigned)col;
}

template <int PASS>
__device__ __forceinline__ void vq_sweep(ScreenShared& sh,
                                         const _Float16* __restrict__ vtb,
                                         float* rb, int w, int l) {
  const int g = l >> 4, ln = l & 15;
  const int swz = (ln & 7) << 2;
  for (int c = 0; c < 8; ++c) {
    const int cb = w * 512 + c * 64;
    float vvc[4];
#pragma unroll
    for (int cf = 0; cf < 4; ++cf) vvc[cf] = sh.vvs[cb + cf * 16 + ln];

    floatx4 acc[8][4];
#pragma unroll
    for (int rf = 0; rf < 8; ++rf)
#pragma unroll
      for (int cf = 0; cf < 4; ++cf) acc[rf][cf] = {0.f, 0.f, 0.f, 0.f};

#pragma unroll
    for (int ks = 0; ks < 8; ++ks) {
      const int s0 = ks * 4 + g;
      const int ch = s0 ^ swz;
      half8 af[8], bf[4];
#pragma unroll
      for (int rf = 0; rf < 8; ++rf)
        af[rf] = *(const half8*)&sh.a[((((rf * 16 + ln) << 5) | ch)) * 8];
#pragma unroll
      for (int cf = 0; cf < 4; ++cf)
        bf[cf] = *(const half8*)(vtb +
            ((size_t)s0 * K_NUM + cb + cf * 16 + ln) * 8);
#pragma unroll
      for (int rf = 0; rf < 8; ++rf)
#pragma unroll
        for (int cf = 0; cf < 4; ++cf)
          acc[rf][cf] = __builtin_amdgcn_mfma_f32_16x16x32_f16(
              af[rf], bf[cf], acc[rf][cf], 0, 0, 0);
    }

#pragma unroll
    for (int rf = 0; rf < 8; ++rf) {
#pragma unroll
      for (int reg = 0; reg < 4; ++reg) {
        // rel-score: vv - 2*dot  (row-constant xx dropped: rank-preserving)
        float s0v = fmaf(-2.0f, acc[rf][0][reg], vvc[0]);
        float s1v = fmaf(-2.0f, acc[rf][1][reg], vvc[1]);
        float s2v = fmaf(-2.0f, acc[rf][2][reg], vvc[2]);
        float s3v = fmaf(-2.0f, acc[rf][3][reg], vvc[3]);
        float m = fminf(fminf(s0v, s1v), fminf(s2v, s3v));
        if (PASS == 1) {
          rb[rf * 4 + reg] = fminf(rb[rf * 4 + reg], m);
        } else {
          float thr = rb[rf * 4 + reg];
          if (m <= thr) {                    // rare (~11%/wave): exec-masked
            const int r = rf * 16 + g * 4 + reg;
            if (s0v <= thr) vq_push(sh, r, cb + 0 * 16 + ln);
            if (s1v <= thr) vq_push(sh, r, cb + 1 * 16 + ln);
            if (s2v <= thr) vq_push(sh, r, cb + 2 * 16 + ln);
            if (s3v <= thr) vq_push(sh, r, cb + 3 * 16 + ln);
          }
        }
      }
    }
  }
}

__global__ __launch_bounds__(512, 2) void vq_screen(
    const float* __restrict__ X, const float* __restrict__ V,
    const _Float16* __restrict__ vtb, const float* __restrict__ vvp,
    const float* __restrict__ xxp, float* __restrict__ idx_out) {
  __shared__ ScreenShared sh;
  const int tid = threadIdx.x;
  const int w = tid >> 6, l = tid & 63;
  const int row0 = blockIdx.x * 128;

  // stage A: f32 -> f16, XOR-swizzled [128 rows][32 x 16B chunks]
#pragma unroll
  for (int it = 0; it < 8; ++it) {
    int idx = it * 512 + tid;
    int r = idx >> 5, s = idx & 31;
    const float* xp = X + (size_t)(row0 + r) * D_DIM + s * 8;
    float4 v0 = *(const float4*)xp, v1 = *(const float4*)(xp + 4);
    half8 h;
    h[0] = (_Float16)v0.x; h[1] = (_Float16)v0.y;
    h[2] = (_Float16)v0.z; h[3] = (_Float16)v0.w;
    h[4] = (_Float16)v1.x; h[5] = (_Float16)v1.y;
    h[6] = (_Float16)v1.z; h[7] = (_Float16)v1.w;
    int slot = (r << 5) | (s ^ ((r & 7) << 2));
    *(half8*)&sh.a[slot * 8] = h;
  }
#pragma unroll
  for (int it = 0; it < 8; ++it) sh.vvs[it * 512 + tid] = vvp[it * 512 + tid];
  if (tid < 128) sh.xxs[tid] = xxp[row0 + tid];
  if (tid == 0) sh.qn = 0;
  __syncthreads();

  float rb[32];
#pragma unroll
  for (int i = 0; i < 32; ++i) rb[i] = INFINITY;

  vq_sweep<1>(sh, vtb, rb, w, l);

  // one shfl-tree per sweep (16-lane groups hold distinct rows)
#pragma unroll
  for (int i = 0; i < 32; ++i) {
#pragma unroll
    for (int off = 1; off <= 8; off <<= 1)
      rb[i] = fminf(rb[i], __shfl_xor(rb[i], off));
  }
  {
    const int g = l >> 4, ln = l & 15;
    if (ln == 0) {
#pragma unroll
      for (int rf = 0; rf < 8; ++rf)
#pragma unroll
        for (int reg = 0; reg < 4; ++reg)
          sh.wmin[w][rf * 16 + g * 4 + reg] = rb[rf * 4 + reg];
    }
  }
  __syncthreads();
  if (tid < 128) {
    float m = sh.wmin[0][tid];
#pragma unroll
    for (int j = 1; j < 8; ++j) m = fminf(m, sh.wmin[j][tid]);
    sh.thr[tid] = m + MARGIN;
  }
  __syncthreads();
  {
    const int g = l >> 4;
#pragma unroll
    for (int rf = 0; rf < 8; ++rf)
#pragma unroll
      for (int reg = 0; reg < 4; ++reg)
        rb[rf * 4 + reg] = sh.thr[rf * 16 + g * 4 + reg];
  }

  vq_sweep<2>(sh, vtb, rb, w, l);
  __syncthreads();

  // exact fp32 rescore (identical arithmetic to the r2-passing kernel)
  const int nq = min(sh.qn, QCAP);
  for (int i = w; i < nq; i += 8) {
    unsigned e = sh.qbuf[i];
    int r = (int)(e >> 12), col = (int)(e & 4095);
    float4 xv = *(const float4*)(X + (size_t)(row0 + r) * D_DIM + l * 4);
    const float* vp = V + col;
    float p = 0.f;
    p = fmaf(xv.x, vp[(size_t)(l * 4 + 0) * K_NUM], p);
    p = fmaf(xv.y, vp[(size_t)(l * 4 + 1) * K_NUM], p);
    p = fmaf(xv.z, vp[(size_t)(l * 4 + 2) * K_NUM], p);
    p = fmaf(xv.w, vp[(size_t)(l * 4 + 3) * K_NUM], p);
#pragma unroll
    for (int off = 1; off < 64; off <<= 1) p += __shfl_xor(p, off);
    float s = __fadd_rn(__fsub_rn(sh.xxs[r], __fmul_rn(2.0f, p)), sh.vvs[col]);
    if (l == 0) sh.qscore[i] = s;
  }
  __syncthreads();

  if (tid < 128) {
    float b = INFINITY;
    int bi = 1 << 30;
    for (int i = 0; i < nq; ++i) {
      unsigned e = sh.qbuf[i];
      if ((int)(e >> 12) == tid) {
        int col = (int)(e & 4095);
        float s = sh.qscore[i];
        if (s < b || (s == b && col < bi)) { b = s; bi = col; }
      }
    }
    idx_out[row0 + tid] = (float)bi;
  }
}

// ---------------- gather + STE + loss ----------------------------------------
// coalesced path: vt is a bit-exact transpose of V -> identical outputs
__global__ __launch_bounds__(256) void vq_gather_vt(const float* __restrict__ A,
                                                    const float* __restrict__ vt,
                                                    const float* __restrict__ idxf,
                                                    float* __restrict__ outq,
                                                    float* __restrict__ loss_sum) {
  int e = blockIdx.x * 256 + threadIdx.x;
  int n = e >> 6;
  int c = (e & 63) << 2;
  int idx = (int)idxf[n];
  float4 xv = *(const float4*)(A + (size_t)n * D_DIM + c);
  float4 qv = *(const float4*)(vt + (size_t)idx * D_DIM + c);
  float4 o;
  o.x = __fadd_rn(xv.x, __fsub_rn(qv.x, xv.x));
  o.y = __fadd_rn(xv.y, __fsub_rn(qv.y, xv.y));
  o.z = __fadd_rn(xv.z, __fsub_rn(qv.z, xv.z));
  o.w = __fadd_rn(xv.w, __fsub_rn(qv.w, xv.w));
  *(float4*)(outq + (size_t)n * D_DIM + c) = o;
  float d0 = __fsub_rn(xv.x, qv.x), d1 = __fsub_rn(xv.y, qv.y);
  float d2 = __fsub_rn(xv.z, qv.z), d3 = __fsub_rn(xv.w, qv.w);
  float ls = d0 * d0 + d1 * d1 + d2 * d2 + d3 * d3;

  __shared__ float red[256];
  red[threadIdx.x] = ls;
  __syncthreads();
  for (int s = 128; s > 0; s >>= 1) {
    if (threadIdx.x < s) red[threadIdx.x] += red[threadIdx.x + s];
    __syncthreads();
  }
  if (threadIdx.x == 0) atomicAdd(loss_sum, red[0]);
}

// fallback (r2-proven) if ws too small for vt
__global__ __launch_bounds__(256) void vq_gather(const float* __restrict__ A,
                                                 const float* __restrict__ V,
                                                 const float* __restrict__ idxf,
                                                 float* __restrict__ outq,
                                                 float* __restrict__ loss_sum) {
  int e = blockIdx.x * 256 + threadIdx.x;
  int n = e >> 6;
  int c = (e & 63) << 2;
  int idx = (int)idxf[n];
  float4 xv = *(const float4*)(A + (size_t)n * D_DIM + c);
  float q0 = V[(size_t)(c + 0) * K_NUM + idx];
  float q1 = V[(size_t)(c + 1) * K_NUM + idx];
  float q2 = V[(size_t)(c + 2) * K_NUM + idx];
  float q3 = V[(size_t)(c + 3) * K_NUM + idx];
  float4 o;
  o.x = __fadd_rn(xv.x, __fsub_rn(q0, xv.x));
  o.y = __fadd_rn(xv.y, __fsub_rn(q1, xv.y));
  o.z = __fadd_rn(xv.z, __fsub_rn(q2, xv.z));
  o.w = __fadd_rn(xv.w, __fsub_rn(q3, xv.w));
  *(float4*)(outq + (size_t)n * D_DIM + c) = o;
  float d0 = __fsub_rn(xv.x, q0), d1 = __fsub_rn(xv.y, q1);
  float d2 = __fsub_rn(xv.z, q2), d3 = __fsub_rn(xv.w, q3);
  float ls = d0 * d0 + d1 * d1 + d2 * d2 + d3 * d3;

  __shared__ float red[256];
  red[threadIdx.x] = ls;
  __syncthreads();
  for (int s = 128; s > 0; s >>= 1) {
    if (threadIdx.x < s) red[threadIdx.x] += red[threadIdx.x + s];
    __syncthreads();
  }
  if (threadIdx.x == 0) atomicAdd(loss_sum, red[0]);
}

__global__ void vq_fin(const float* __restrict__ loss_sum,
                       float* __restrict__ out_losses) {
  float m = loss_sum[0] / 8388608.0f;
  out_losses[0] = m;
  out_losses[1] = m;
}

extern "C" void kernel_launch(void* const* d_in, const int* in_sizes, int n_in,
                              void* d_out, int out_size, void* d_ws, size_t ws_size,
                              hipStream_t stream) {
  const float* x = (const float*)d_in[0];
  const float* V = (const float*)d_in[1];
  float* out = (float*)d_out;
  float* outq    = out;
  float* outloss = out + 8388608;
  float* outidx  = out + 8388610;

  // ws layout
  float* ws_vv  = (float*)d_ws;                          // 16 KB
  float* ws_xx  = ws_vv + K_NUM;                         // 128 KB
  float* ws_sum = ws_xx + N_ROWS;                        // 4 B
  _Float16* ws_vtb = (_Float16*)((char*)d_ws + 163840);  // 2 MB
  float* ws_vt = (float*)((char*)d_ws + 163840 + 2097152);  // 4 MB
  const int have_vt = (ws_size >= (size_t)(163840 + 2097152 + 4194304));

  hipMemsetAsync(ws_sum, 0, sizeof(float), stream);
  vq_vv    <<<K_NUM / 256, 256, 0, stream>>>(V, ws_vv);
  vq_xx    <<<N_ROWS / 256, 256, 0, stream>>>(x, ws_xx);
  vq_prep  <<<K_NUM / 64, 256, 0, stream>>>(V, ws_vtb, ws_vt, have_vt);
  vq_screen<<<N_ROWS / 128, 512, 0, stream>>>(x, V, ws_vtb, ws_vv, ws_xx, outidx);
  if (have_vt)
    vq_gather_vt<<<(N_ROWS * (D_DIM / 4)) / 256, 256, 0, stream>>>(
        x, ws_vt, outidx, outq, ws_sum);
  else
    vq_gather<<<(N_ROWS * (D_DIM / 4)) / 256, 256, 0, stream>>>(
        x, V, outidx, outq, ws_sum);
  vq_fin   <<<1, 1, 0, stream>>>(ws_sum, outloss);
}

// Round 4
// 329.537 us; speedup vs baseline: 1.5373x; 1.5373x over previous
//
#include <hip/hip_runtime.h>
#include <math.h>

#define D_DIM 256
#define K_NUM 4096
#define N_ROWS 32768
#define QCAP 640
#define MARGIN 0.02f

typedef _Float16 half8 __attribute__((ext_vector_type(8)));
typedef float floatx4 __attribute__((ext_vector_type(4)));

// numpy pairwise sum-of-squares over 128 floats (unchanged, passed r1-r3)
__device__ inline float np_pw128_sumsq(const float* __restrict__ p) {
  float r[8];
  float4 a = *(const float4*)p, b = *(const float4*)(p + 4);
  r[0] = __fmul_rn(a.x, a.x); r[1] = __fmul_rn(a.y, a.y);
  r[2] = __fmul_rn(a.z, a.z); r[3] = __fmul_rn(a.w, a.w);
  r[4] = __fmul_rn(b.x, b.x); r[5] = __fmul_rn(b.y, b.y);
  r[6] = __fmul_rn(b.z, b.z); r[7] = __fmul_rn(b.w, b.w);
#pragma unroll
  for (int i = 8; i < 128; i += 8) {
    a = *(const float4*)(p + i); b = *(const float4*)(p + i + 4);
    r[0] = __fadd_rn(r[0], __fmul_rn(a.x, a.x));
    r[1] = __fadd_rn(r[1], __fmul_rn(a.y, a.y));
    r[2] = __fadd_rn(r[2], __fmul_rn(a.z, a.z));
    r[3] = __fadd_rn(r[3], __fmul_rn(a.w, a.w));
    r[4] = __fadd_rn(r[4], __fmul_rn(b.x, b.x));
    r[5] = __fadd_rn(r[5], __fmul_rn(b.y, b.y));
    r[6] = __fadd_rn(r[6], __fmul_rn(b.z, b.z));
    r[7] = __fadd_rn(r[7], __fmul_rn(b.w, b.w));
  }
  float t01 = __fadd_rn(r[0], r[1]);
  float t23 = __fadd_rn(r[2], r[3]);
  float t45 = __fadd_rn(r[4], r[5]);
  float t67 = __fadd_rn(r[6], r[7]);
  return __fadd_rn(__fadd_rn(t01, t23), __fadd_rn(t45, t67));
}

__global__ __launch_bounds__(256) void vq_xx(const float* __restrict__ X,
                                             float* __restrict__ xx) {
  int n = blockIdx.x * 256 + threadIdx.x;
  const float* p = X + (size_t)n * D_DIM;
  xx[n] = __fadd_rn(np_pw128_sumsq(p), np_pw128_sumsq(p + 128));
}

// ---- V [256][4096] -> vtb f16 [dc][col][8], vt f32 [4096][256], vv[k] -------
__global__ __launch_bounds__(256) void vq_prep(const float* __restrict__ V,
                                               _Float16* __restrict__ vtb,
                                               float* __restrict__ vt,
                                               float* __restrict__ vv,
                                               int write_vt) {
  __shared__ float tile[256][64];   // 64 KB
  const int col0 = blockIdx.x * 64;
  const int cq = threadIdx.x >> 6;  // 0..3
  const int cl = threadIdx.x & 63;
#pragma unroll
  for (int it = 0; it < 64; ++it) {
    int d = it * 4 + cq;
    tile[d][cl] = V[(size_t)d * K_NUM + col0 + cl];
  }
  __syncthreads();
#pragma unroll
  for (int q = 0; q < 8; ++q) {
    int dc = q * 4 + cq;            // 0..31
    half8 h;
#pragma unroll
    for (int j = 0; j < 8; ++j) h[j] = (_Float16)tile[dc * 8 + j][cl];
    *(half8*)(vtb + ((size_t)dc * K_NUM + col0 + cl) * 8) = h;
  }
  if (cq == 0) {  // vv: bit-exact sequential d-order (matches r1-proven vq_vv)
    float acc = 0.0f;
    for (int d = 0; d < D_DIM; ++d) {
      float v = tile[d][cl];
      acc = __fadd_rn(acc, __fmul_rn(v, v));
    }
    vv[col0 + cl] = acc;
  }
  if (write_vt) {
#pragma unroll
    for (int j = 0; j < 16; ++j) {
      int d0 = cq * 64 + j * 4;
      float4 f;
      f.x = tile[d0 + 0][cl]; f.y = tile[d0 + 1][cl];
      f.z = tile[d0 + 2][cl]; f.w = tile[d0 + 3][cl];
      *(float4*)(vt + (size_t)(col0 + cl) * D_DIM + d0) = f;
    }
  }
}

// ---------------- fp16 MFMA screen: 64 rows, 8 col-group waves, rf4/cf2 ------
struct alignas(16) ScreenShared {
  _Float16 a[64 * 256];    // 32 KB, low-bit XOR-swizzled
  float vvs[K_NUM];        // 16 KB
  float xxs[64];
  float wmin[8][64];       // 2 KB
  float thr[64];
  float cmin[8][16];       // per-(wave,c-iter) min for sweep-2 skip
  float thrmax;
  unsigned qbuf[QCAP];
  float qscore[QCAP];
  int qn;
};

__device__ __forceinline__ void vq_push(ScreenShared& sh, int r, int col) {
  int u = atomicAdd(&sh.qn, 1);
  if (u < QCAP) sh.qbuf[u] = ((unsigned)r << 12) | (unsigned)col;
}

template <int PASS>
__device__ __forceinline__ void vq_sweep(ScreenShared& sh,
                                         const _Float16* __restrict__ vtb,
                                         float* rb, int w, int l) {
  const int g = l >> 4, ln = l & 15;
  for (int c = 0; c < 16; ++c) {
    if (PASS == 2) {
      if (sh.cmin[w][c] > sh.thrmax) continue;   // wave-uniform skip
    }
    const int cb = w * 512 + c * 32;
    const float vv0 = sh.vvs[cb + ln];
    const float vv1 = sh.vvs[cb + 16 + ln];

    floatx4 acc[4][2];
#pragma unroll
    for (int rf = 0; rf < 4; ++rf)
#pragma unroll
      for (int cf = 0; cf < 2; ++cf) acc[rf][cf] = {0.f, 0.f, 0.f, 0.f};

#pragma unroll
    for (int ks = 0; ks < 8; ++ks) {
      const int s0 = ks * 4 + g;
      const int ch = s0 ^ (ln & 7);              // low-bit swizzle: bank-clean
      const _Float16* abase = &sh.a[((ln << 5) | ch) * 8];
      const _Float16* bbase = vtb + ((size_t)s0 * K_NUM + cb + ln) * 8;
      half8 af[4], bf[2];
#pragma unroll
      for (int rf = 0; rf < 4; ++rf)
        af[rf] = *(const half8*)(abase + rf * 4096);   // +8 KB ds offsets
      bf[0] = *(const half8*)bbase;
      bf[1] = *(const half8*)(bbase + 128);
#pragma unroll
      for (int rf = 0; rf < 4; ++rf)
#pragma unroll
        for (int cf = 0; cf < 2; ++cf)
          acc[rf][cf] = __builtin_amdgcn_mfma_f32_16x16x32_f16(
              af[rf], bf[cf], acc[rf][cf], 0, 0, 0);
    }

    float m16 = INFINITY;
#pragma unroll
    for (int rf = 0; rf < 4; ++rf) {
#pragma unroll
      for (int reg = 0; reg < 4; ++reg) {
        float s0v = fmaf(-2.0f, acc[rf][0][reg], vv0);
        float s1v = fmaf(-2.0f, acc[rf][1][reg], vv1);
        float m = fminf(s0v, s1v);
        if (PASS == 1) {
          rb[rf * 4 + reg] = fminf(rb[rf * 4 + reg], m);
          m16 = fminf(m16, m);
        } else {
          float thr = rb[rf * 4 + reg];
          if (m <= thr) {                    // rare: exec-masked
            const int r = rf * 16 + g * 4 + reg;
            if (s0v <= thr) vq_push(sh, r, cb + ln);
            if (s1v <= thr) vq_push(sh, r, cb + 16 + ln);
          }
        }
      }
    }
    if (PASS == 1) {
#pragma unroll
      for (int off = 1; off < 64; off <<= 1)
        m16 = fminf(m16, __shfl_xor(m16, off));
      if (l == 0) sh.cmin[w][c] = m16;
    }
  }
}

__global__ __launch_bounds__(512, 4) void vq_screen(
    const float* __restrict__ X, const float* __restrict__ V,
    const _Float16* __restrict__ vtb, const float* __restrict__ vvp,
    const float* __restrict__ xxp, float* __restrict__ idx_out) {
  __shared__ ScreenShared sh;
  const int tid = threadIdx.x;
  const int w = tid >> 6, l = tid & 63;
  const int row0 = blockIdx.x * 64;

  // stage A: f32 -> f16, low-bit XOR-swizzled [64 rows][32 x 16B chunks]
#pragma unroll
  for (int it = 0; it < 4; ++it) {
    int idx = it * 512 + tid;
    int r = idx >> 5, s = idx & 31;
    const float* xp = X + (size_t)(row0 + r) * D_DIM + s * 8;
    float4 v0 = *(const float4*)xp, v1 = *(const float4*)(xp + 4);
    half8 h;
    h[0] = (_Float16)v0.x; h[1] = (_Float16)v0.y;
    h[2] = (_Float16)v0.z; h[3] = (_Float16)v0.w;
    h[4] = (_Float16)v1.x; h[5] = (_Float16)v1.y;
    h[6] = (_Float16)v1.z; h[7] = (_Float16)v1.w;
    int slot = (r << 5) | (s ^ (r & 7));
    *(half8*)&sh.a[slot * 8] = h;
  }
#pragma unroll
  for (int it = 0; it < 8; ++it) sh.vvs[it * 512 + tid] = vvp[it * 512 + tid];
  if (tid < 64) sh.xxs[tid] = xxp[row0 + tid];
  if (tid == 0) sh.qn = 0;
  __syncthreads();

  float rb[16];
#pragma unroll
  for (int i = 0; i < 16; ++i) rb[i] = INFINITY;

  vq_sweep<1>(sh, vtb, rb, w, l);

  // lane-reduce per-(rf,reg) mins over the 16 ln lanes (same rows)
#pragma unroll
  for (int i = 0; i < 16; ++i) {
#pragma unroll
    for (int off = 1; off <= 8; off <<= 1)
      rb[i] = fminf(rb[i], __shfl_xor(rb[i], off));
  }
  {
    const int g = l >> 4, ln = l & 15;
    if (ln == 0) {
#pragma unroll
      for (int rf = 0; rf < 4; ++rf)
#pragma unroll
        for (int reg = 0; reg < 4; ++reg)
          sh.wmin[w][rf * 16 + g * 4 + reg] = rb[rf * 4 + reg];
    }
  }
  __syncthreads();
  if (tid < 64) {
    float m = sh.wmin[0][tid];
#pragma unroll
    for (int j = 1; j < 8; ++j) m = fminf(m, sh.wmin[j][tid]);
    float t = m + MARGIN;
    sh.thr[tid] = t;
    // block max of thr via wave 0 shuffle
#pragma unroll
    for (int off = 1; off < 64; off <<= 1)
      t = fmaxf(t, __shfl_xor(t, off));
    if (tid == 0) sh.thrmax = t;
  }
  __syncthreads();
  {
    const int g = l >> 4;
#pragma unroll
    for (int rf = 0; rf < 4; ++rf)
#pragma unroll
      for (int reg = 0; reg < 4; ++reg)
        rb[rf * 4 + reg] = sh.thr[rf * 16 + g * 4 + reg];
  }

  vq_sweep<2>(sh, vtb, rb, w, l);
  __syncthreads();

  // exact fp32 rescore (identical arithmetic to the r2/r3-passing kernels)
  const int nq = min(sh.qn, QCAP);
  for (int i = w; i < nq; i += 8) {
    unsigned e = sh.qbuf[i];
    int r = (int)(e >> 12), col = (int)(e & 4095);
    float4 xv = *(const float4*)(X + (size_t)(row0 + r) * D_DIM + l * 4);
    const float* vp = V + col;
    float p = 0.f;
    p = fmaf(xv.x, vp[(size_t)(l * 4 + 0) * K_NUM], p);
    p = fmaf(xv.y, vp[(size_t)(l * 4 + 1) * K_NUM], p);
    p = fmaf(xv.z, vp[(size_t)(l * 4 + 2) * K_NUM], p);
    p = fmaf(xv.w, vp[(size_t)(l * 4 + 3) * K_NUM], p);
#pragma unroll
    for (int off = 1; off < 64; off <<= 1) p += __shfl_xor(p, off);
    float s = __fadd_rn(__fsub_rn(sh.xxs[r], __fmul_rn(2.0f, p)), sh.vvs[col]);
    if (l == 0) sh.qscore[i] = s;
  }
  __syncthreads();

  if (tid < 64) {
    float b = INFINITY;
    int bi = 1 << 30;
    for (int i = 0; i < nq; ++i) {
      unsigned e = sh.qbuf[i];
      if ((int)(e >> 12) == tid) {
        int col = (int)(e & 4095);
        float s = sh.qscore[i];
        if (s < b || (s == b && col < bi)) { b = s; bi = col; }
      }
    }
    idx_out[row0 + tid] = (float)bi;
  }
}

// ---------------- gather + STE + loss (r2/r3-proven) -------------------------
__global__ __launch_bounds__(256) void vq_gather_vt(const float* __restrict__ A,
                                                    const float* __restrict__ vt,
                                                    const float* __restrict__ idxf,
                                                    float* __restrict__ outq,
                                                    float* __restrict__ loss_sum) {
  int e = blockIdx.x * 256 + threadIdx.x;
  int n = e >> 6;
  int c = (e & 63) << 2;
  int idx = (int)idxf[n];
  float4 xv = *(const float4*)(A + (size_t)n * D_DIM + c);
  float4 qv = *(const float4*)(vt + (size_t)idx * D_DIM + c);
  float4 o;
  o.x = __fadd_rn(xv.x, __fsub_rn(qv.x, xv.x));
  o.y = __fadd_rn(xv.y, __fsub_rn(qv.y, xv.y));
  o.z = __fadd_rn(xv.z, __fsub_rn(qv.z, xv.z));
  o.w = __fadd_rn(xv.w, __fsub_rn(qv.w, xv.w));
  *(float4*)(outq + (size_t)n * D_DIM + c) = o;
  float d0 = __fsub_rn(xv.x, qv.x), d1 = __fsub_rn(xv.y, qv.y);
  float d2 = __fsub_rn(xv.z, qv.z), d3 = __fsub_rn(xv.w, qv.w);
  float ls = d0 * d0 + d1 * d1 + d2 * d2 + d3 * d3;

  __shared__ float red[256];
  red[threadIdx.x] = ls;
  __syncthreads();
  for (int s = 128; s > 0; s >>= 1) {
    if (threadIdx.x < s) red[threadIdx.x] += red[threadIdx.x + s];
    __syncthreads();
  }
  if (threadIdx.x == 0) atomicAdd(loss_sum, red[0]);
}

__global__ __launch_bounds__(256) void vq_gather(const float* __restrict__ A,
                                                 const float* __restrict__ V,
                                                 const float* __restrict__ idxf,
                                                 float* __restrict__ outq,
                                                 float* __restrict__ loss_sum) {
  int e = blockIdx.x * 256 + threadIdx.x;
  int n = e >> 6;
  int c = (e & 63) << 2;
  int idx = (int)idxf[n];
  float4 xv = *(const float4*)(A + (size_t)n * D_DIM + c);
  float q0 = V[(size_t)(c + 0) * K_NUM + idx];
  float q1 = V[(size_t)(c + 1) * K_NUM + idx];
  float q2 = V[(size_t)(c + 2) * K_NUM + idx];
  float q3 = V[(size_t)(c + 3) * K_NUM + idx];
  float4 o;
  o.x = __fadd_rn(xv.x, __fsub_rn(q0, xv.x));
  o.y = __fadd_rn(xv.y, __fsub_rn(q1, xv.y));
  o.z = __fadd_rn(xv.z, __fsub_rn(q2, xv.z));
  o.w = __fadd_rn(xv.w, __fsub_rn(q3, xv.w));
  *(float4*)(outq + (size_t)n * D_DIM + c) = o;
  float d0 = __fsub_rn(xv.x, q0), d1 = __fsub_rn(xv.y, q1);
  float d2 = __fsub_rn(xv.z, q2), d3 = __fsub_rn(xv.w, q3);
  float ls = d0 * d0 + d1 * d1 + d2 * d2 + d3 * d3;

  __shared__ float red[256];
  red[threadIdx.x] = ls;
  __syncthreads();
  for (int s = 128; s > 0; s >>= 1) {
    if (threadIdx.x < s) red[threadIdx.x] += red[threadIdx.x + s];
    __syncthreads();
  }
  if (threadIdx.x == 0) atomicAdd(loss_sum, red[0]);
}

__global__ void vq_fin(const float* __restrict__ loss_sum,
                       float* __restrict__ out_losses) {
  float m = loss_sum[0] / 8388608.0f;
  out_losses[0] = m;
  out_losses[1] = m;
}

extern "C" void kernel_launch(void* const* d_in, const int* in_sizes, int n_in,
                              void* d_out, int out_size, void* d_ws, size_t ws_size,
                              hipStream_t stream) {
  const float* x = (const float*)d_in[0];
  const float* V = (const float*)d_in[1];
  float* out = (float*)d_out;
  float* outq    = out;
  float* outloss = out + 8388608;
  float* outidx  = out + 8388610;

  float* ws_vv  = (float*)d_ws;                          // 16 KB
  float* ws_xx  = ws_vv + K_NUM;                         // 128 KB
  float* ws_sum = ws_xx + N_ROWS;                        // 4 B
  _Float16* ws_vtb = (_Float16*)((char*)d_ws + 163840);  // 2 MB
  float* ws_vt = (float*)((char*)d_ws + 163840 + 2097152);  // 4 MB
  const int have_vt = (ws_size >= (size_t)(163840 + 2097152 + 4194304));

  hipMemsetAsync(ws_sum, 0, sizeof(float), stream);
  vq_xx    <<<N_ROWS / 256, 256, 0, stream>>>(x, ws_xx);
  vq_prep  <<<K_NUM / 64, 256, 0, stream>>>(V, ws_vtb, ws_vt, ws_vv, have_vt);
  vq_screen<<<N_ROWS / 64, 512, 0, stream>>>(x, V, ws_vtb, ws_vv, ws_xx, outidx);
  if (have_vt)
    vq_gather_vt<<<(N_ROWS * (D_DIM / 4)) / 256, 256, 0, stream>>>(
        x, ws_vt, outidx, outq, ws_sum);
  else
    vq_gather<<<(N_ROWS * (D_DIM / 4)) / 256, 256, 0, stream>>>(
        x, V, outidx, outq, ws_sum);
  vq_fin   <<<1, 1, 0, stream>>>(ws_sum, outloss);
}

// Round 5
// 289.572 us; speedup vs baseline: 1.7495x; 1.1380x over previous
//
#include <hip/hip_runtime.h>
#include <math.h>

#define D_DIM 256
#define K_NUM 4096
#define N_ROWS 32768
#define QCAP 3072
#define MARGIN 0.02f

typedef _Float16 half8 __attribute__((ext_vector_type(8)));
typedef float floatx4 __attribute__((ext_vector_type(4)));

// ---------------- vv[k] = sum_d V[d][k]^2 (r1-proven exact order) ------------
__global__ __launch_bounds__(256) void vq_vv(const float* __restrict__ V,
                                             float* __restrict__ vv) {
  int k = blockIdx.x * 256 + threadIdx.x;
  float acc = 0.0f;
  for (int d = 0; d < D_DIM; ++d) {
    float v = V[(size_t)d * K_NUM + k];
    acc = __fadd_rn(acc, __fmul_rn(v, v));
  }
  vv[k] = acc;
}

// numpy pairwise sum-of-squares over 128 floats (r1-r4-proven)
__device__ inline float np_pw128_sumsq(const float* __restrict__ p) {
  float r[8];
  float4 a = *(const float4*)p, b = *(const float4*)(p + 4);
  r[0] = __fmul_rn(a.x, a.x); r[1] = __fmul_rn(a.y, a.y);
  r[2] = __fmul_rn(a.z, a.z); r[3] = __fmul_rn(a.w, a.w);
  r[4] = __fmul_rn(b.x, b.x); r[5] = __fmul_rn(b.y, b.y);
  r[6] = __fmul_rn(b.z, b.z); r[7] = __fmul_rn(b.w, b.w);
#pragma unroll
  for (int i = 8; i < 128; i += 8) {
    a = *(const float4*)(p + i); b = *(const float4*)(p + i + 4);
    r[0] = __fadd_rn(r[0], __fmul_rn(a.x, a.x));
    r[1] = __fadd_rn(r[1], __fmul_rn(a.y, a.y));
    r[2] = __fadd_rn(r[2], __fmul_rn(a.z, a.z));
    r[3] = __fadd_rn(r[3], __fmul_rn(a.w, a.w));
    r[4] = __fadd_rn(r[4], __fmul_rn(b.x, b.x));
    r[5] = __fadd_rn(r[5], __fmul_rn(b.y, b.y));
    r[6] = __fadd_rn(r[6], __fmul_rn(b.z, b.z));
    r[7] = __fadd_rn(r[7], __fmul_rn(b.w, b.w));
  }
  float t01 = __fadd_rn(r[0], r[1]);
  float t23 = __fadd_rn(r[2], r[3]);
  float t45 = __fadd_rn(r[4], r[5]);
  float t67 = __fadd_rn(r[6], r[7]);
  return __fadd_rn(__fadd_rn(t01, t23), __fadd_rn(t45, t67));
}

// ---- V quadrant transpose: 256 blocks of (64 cols x 64 d) -> vtb f16, vt f32
__global__ __launch_bounds__(256) void vq_prep(const float* __restrict__ V,
                                               _Float16* __restrict__ vtb,
                                               float* __restrict__ vt,
                                               int write_vt) {
  __shared__ float tile[64][64];      // [d_local][col_local] 16 KB
  const int col0 = (blockIdx.x & 63) * 64;
  const int d0 = (blockIdx.x >> 6) * 64;
  const int cq = threadIdx.x >> 6;    // 0..3
  const int cl = threadIdx.x & 63;
#pragma unroll
  for (int it = 0; it < 16; ++it) {
    int d = it * 4 + cq;
    tile[d][cl] = V[(size_t)(d0 + d) * K_NUM + col0 + cl];
  }
  __syncthreads();
#pragma unroll
  for (int qq = 0; qq < 2; ++qq) {
    int q = cq * 2 + qq;              // 0..7 local d-chunk
    half8 h;
#pragma unroll
    for (int j = 0; j < 8; ++j) h[j] = (_Float16)tile[q * 8 + j][cl];
    *(half8*)(vtb + ((size_t)(d0 / 8 + q) * K_NUM + col0 + cl) * 8) = h;
  }
  if (write_vt) {
#pragma unroll
    for (int j = 0; j < 4; ++j) {
      int d = cq * 16 + j * 4;
      float4 f;
      f.x = tile[d + 0][cl]; f.y = tile[d + 1][cl];
      f.z = tile[d + 2][cl]; f.w = tile[d + 3][cl];
      *(float4*)(vt + (size_t)(col0 + cl) * D_DIM + d0 + d) = f;
    }
  }
}

// ---------------- fp16 MFMA screen: pass0 threshold + single collect sweep ---
struct alignas(16) ScreenShared {
  _Float16 a[64 * 256];    // 32 KB, low-bit XOR-swizzled
  float vvs[K_NUM];        // 16 KB
  float xxs[64];
  float wmin[8][64];       // 2 KB
  float thr[64];
  unsigned long long best[64];   // (score_bits<<32)|col per row
  unsigned qbuf[QCAP];     // 12 KB
  int qn;
};

__device__ __forceinline__ void vq_push(ScreenShared& sh, int r, int col) {
  int u = atomicAdd(&sh.qn, 1);
  if (u < QCAP) sh.qbuf[u] = ((unsigned)r << 12) | (unsigned)col;
}

// MODE 0: fold cell mins into tb[16].  MODE 1: collect cols with s <= tb.
template <int MODE>
__device__ __forceinline__ void vq_cell(ScreenShared& sh,
                                        const _Float16* __restrict__ vtb,
                                        float* tb, int w, int l, int c) {
  const int g = l >> 4, ln = l & 15;
  const int cb = w * 512 + c * 32;
  const float vv0 = sh.vvs[cb + ln];
  const float vv1 = sh.vvs[cb + 16 + ln];

  floatx4 acc[4][2];
#pragma unroll
  for (int rf = 0; rf < 4; ++rf)
#pragma unroll
    for (int cf = 0; cf < 2; ++cf) acc[rf][cf] = {0.f, 0.f, 0.f, 0.f};

#pragma unroll
  for (int ks = 0; ks < 8; ++ks) {
    const int s0 = ks * 4 + g;
    const int ch = s0 ^ (ln & 7);
    const _Float16* abase = &sh.a[((ln << 5) | ch) * 8];
    const _Float16* bbase = vtb + ((size_t)s0 * K_NUM + cb + ln) * 8;
    half8 af[4], bf[2];
#pragma unroll
    for (int rf = 0; rf < 4; ++rf)
      af[rf] = *(const half8*)(abase + rf * 4096);
    bf[0] = *(const half8*)bbase;
    bf[1] = *(const half8*)(bbase + 128);
#pragma unroll
    for (int rf = 0; rf < 4; ++rf)
#pragma unroll
      for (int cf = 0; cf < 2; ++cf)
        acc[rf][cf] = __builtin_amdgcn_mfma_f32_16x16x32_f16(
            af[rf], bf[cf], acc[rf][cf], 0, 0, 0);
  }

#pragma unroll
  for (int rf = 0; rf < 4; ++rf) {
#pragma unroll
    for (int reg = 0; reg < 4; ++reg) {
      float s0v = fmaf(-2.0f, acc[rf][0][reg], vv0);
      float s1v = fmaf(-2.0f, acc[rf][1][reg], vv1);
      float m = fminf(s0v, s1v);
      if (MODE == 0) {
        tb[rf * 4 + reg] = fminf(tb[rf * 4 + reg], m);
      } else {
        float thr = tb[rf * 4 + reg];
        if (m <= thr) {                  // rare: exec-masked push
          const int r = rf * 16 + g * 4 + reg;
          if (s0v <= thr) vq_push(sh, r, cb + ln);
          if (s1v <= thr) vq_push(sh, r, cb + 16 + ln);
        }
      }
    }
  }
}

__global__ __launch_bounds__(512, 4) void vq_screen(
    const float* __restrict__ X, const float* __restrict__ V,
    const _Float16* __restrict__ vtb, const float* __restrict__ vvp,
    const float* __restrict__ vt, float* __restrict__ idx_out) {
  __shared__ ScreenShared sh;
  const int tid = threadIdx.x;
  const int w = tid >> 6, l = tid & 63;
  const int row0 = blockIdx.x * 64;

  // stage A: f32 -> f16, low-bit XOR-swizzled
#pragma unroll
  for (int it = 0; it < 4; ++it) {
    int idx = it * 512 + tid;
    int r = idx >> 5, s = idx & 31;
    const float* xp = X + (size_t)(row0 + r) * D_DIM + s * 8;
    float4 v0 = *(const float4*)xp, v1 = *(const float4*)(xp + 4);
    half8 h;
    h[0] = (_Float16)v0.x; h[1] = (_Float16)v0.y;
    h[2] = (_Float16)v0.z; h[3] = (_Float16)v0.w;
    h[4] = (_Float16)v1.x; h[5] = (_Float16)v1.y;
    h[6] = (_Float16)v1.z; h[7] = (_Float16)v1.w;
    int slot = (r << 5) | (s ^ (r & 7));
    *(half8*)&sh.a[slot * 8] = h;
  }
#pragma unroll
  for (int it = 0; it < 8; ++it) sh.vvs[it * 512 + tid] = vvp[it * 512 + tid];
  // exact numpy-pairwise ||x||^2, 8 lanes per wave (feeds rescore only)
  if ((tid & 7) == 0) {
    int r = tid >> 3;
    const float* ap = X + (size_t)(row0 + r) * D_DIM;
    sh.xxs[r] = __fadd_rn(np_pw128_sumsq(ap), np_pw128_sumsq(ap + 128));
  }
  if (tid < 64) sh.best[tid] = 0xFFFFFFFFFFFFFFFFull;
  if (tid == 0) sh.qn = 0;
  __syncthreads();

  float tb[16];
#pragma unroll
  for (int i = 0; i < 16; ++i) tb[i] = INFINITY;

  // pass0: subsampled threshold (c-iters 0 and 8 -> 64 of this wave's 512 cols)
  vq_cell<0>(sh, vtb, tb, w, l, 0);
  vq_cell<0>(sh, vtb, tb, w, l, 8);

  // reduce per-row mins across the 16 ln-lanes (masks <16 stay within group)
#pragma unroll
  for (int i = 0; i < 16; ++i) {
#pragma unroll
    for (int off = 1; off <= 8; off <<= 1)
      tb[i] = fminf(tb[i], __shfl_xor(tb[i], off));
  }
  {
    const int g = l >> 4, ln = l & 15;
    if (ln == 0) {
#pragma unroll
      for (int rf = 0; rf < 4; ++rf)
#pragma unroll
        for (int reg = 0; reg < 4; ++reg)
          sh.wmin[w][rf * 16 + g * 4 + reg] = tb[rf * 4 + reg];
    }
  }
  __syncthreads();
  if (tid < 64) {
    float m = sh.wmin[0][tid];
#pragma unroll
    for (int j = 1; j < 8; ++j) m = fminf(m, sh.wmin[j][tid]);
    sh.thr[tid] = m + MARGIN;
  }
  __syncthreads();
  {
    const int g = l >> 4;
#pragma unroll
    for (int rf = 0; rf < 4; ++rf)
#pragma unroll
      for (int reg = 0; reg < 4; ++reg)
        tb[rf * 4 + reg] = sh.thr[rf * 16 + g * 4 + reg];
  }

  // single full sweep, fixed threshold, collect candidates
  for (int c = 0; c < 16; ++c) vq_cell<1>(sh, vtb, tb, w, l, c);
  __syncthreads();

  // exact fp32 rescore (same fma/shfl order as r2-r4-proven rescore)
  const int nq = min(sh.qn, QCAP);
  for (int i = w; i < nq; i += 8) {
    unsigned e = sh.qbuf[i];
    int r = (int)(e >> 12), col = (int)(e & 4095);
    float4 xv = *(const float4*)(X + (size_t)(row0 + r) * D_DIM + l * 4);
    float p = 0.f;
    if (vt) {
      float4 qv = *(const float4*)(vt + (size_t)col * D_DIM + l * 4);
      p = fmaf(xv.x, qv.x, p);
      p = fmaf(xv.y, qv.y, p);
      p = fmaf(xv.z, qv.z, p);
      p = fmaf(xv.w, qv.w, p);
    } else {
      const float* vp = V + col;
      p = fmaf(xv.x, vp[(size_t)(l * 4 + 0) * K_NUM], p);
      p = fmaf(xv.y, vp[(size_t)(l * 4 + 1) * K_NUM], p);
      p = fmaf(xv.z, vp[(size_t)(l * 4 + 2) * K_NUM], p);
      p = fmaf(xv.w, vp[(size_t)(l * 4 + 3) * K_NUM], p);
    }
#pragma unroll
    for (int off = 1; off < 64; off <<= 1) p += __shfl_xor(p, off);
    if (l == 0) {
      float s = __fadd_rn(__fsub_rn(sh.xxs[r], __fmul_rn(2.0f, p)),
                          sh.vvs[col]);
      unsigned long long key =
          ((unsigned long long)__float_as_uint(s) << 32) | (unsigned)col;
      atomicMin(&sh.best[r], key);
    }
  }
  __syncthreads();

  if (tid < 64)
    idx_out[row0 + tid] = (float)(unsigned)(sh.best[tid] & 0xFFFFFFFFu);
}

// ---------------- gather + STE + loss (r2-r4-proven) -------------------------
__global__ __launch_bounds__(256) void vq_gather_vt(const float* __restrict__ A,
                                                    const float* __restrict__ vt,
                                                    const float* __restrict__ idxf,
                                                    float* __restrict__ outq,
                                                    float* __restrict__ loss_sum) {
  int e = blockIdx.x * 256 + threadIdx.x;
  int n = e >> 6;
  int c = (e & 63) << 2;
  int idx = (int)idxf[n];
  float4 xv = *(const float4*)(A + (size_t)n * D_DIM + c);
  float4 qv = *(const float4*)(vt + (size_t)idx * D_DIM + c);
  float4 o;
  o.x = __fadd_rn(xv.x, __fsub_rn(qv.x, xv.x));
  o.y = __fadd_rn(xv.y, __fsub_rn(qv.y, xv.y));
  o.z = __fadd_rn(xv.z, __fsub_rn(qv.z, xv.z));
  o.w = __fadd_rn(xv.w, __fsub_rn(qv.w, xv.w));
  *(float4*)(outq + (size_t)n * D_DIM + c) = o;
  float d0 = __fsub_rn(xv.x, qv.x), d1 = __fsub_rn(xv.y, qv.y);
  float d2 = __fsub_rn(xv.z, qv.z), d3 = __fsub_rn(xv.w, qv.w);
  float ls = d0 * d0 + d1 * d1 + d2 * d2 + d3 * d3;

  __shared__ float red[256];
  red[threadIdx.x] = ls;
  __syncthreads();
  for (int s = 128; s > 0; s >>= 1) {
    if (threadIdx.x < s) red[threadIdx.x] += red[threadIdx.x + s];
    __syncthreads();
  }
  if (threadIdx.x == 0) atomicAdd(loss_sum, red[0]);
}

__global__ __launch_bounds__(256) void vq_gather(const float* __restrict__ A,
                                                 const float* __restrict__ V,
                                                 const float* __restrict__ idxf,
                                                 float* __restrict__ outq,
                                                 float* __restrict__ loss_sum) {
  int e = blockIdx.x * 256 + threadIdx.x;
  int n = e >> 6;
  int c = (e & 63) << 2;
  int idx = (int)idxf[n];
  float4 xv = *(const float4*)(A + (size_t)n * D_DIM + c);
  float q0 = V[(size_t)(c + 0) * K_NUM + idx];
  float q1 = V[(size_t)(c + 1) * K_NUM + idx];
  float q2 = V[(size_t)(c + 2) * K_NUM + idx];
  float q3 = V[(size_t)(c + 3) * K_NUM + idx];
  float4 o;
  o.x = __fadd_rn(xv.x, __fsub_rn(q0, xv.x));
  o.y = __fadd_rn(xv.y, __fsub_rn(q1, xv.y));
  o.z = __fadd_rn(xv.z, __fsub_rn(q2, xv.z));
  o.w = __fadd_rn(xv.w, __fsub_rn(q3, xv.w));
  *(float4*)(outq + (size_t)n * D_DIM + c) = o;
  float d0 = __fsub_rn(xv.x, q0), d1 = __fsub_rn(xv.y, q1);
  float d2 = __fsub_rn(xv.z, q2), d3 = __fsub_rn(xv.w, q3);
  float ls = d0 * d0 + d1 * d1 + d2 * d2 + d3 * d3;

  __shared__ float red[256];
  red[threadIdx.x] = ls;
  __syncthreads();
  for (int s = 128; s > 0; s >>= 1) {
    if (threadIdx.x < s) red[threadIdx.x] += red[threadIdx.x + s];
    __syncthreads();
  }
  if (threadIdx.x == 0) atomicAdd(loss_sum, red[0]);
}

__global__ void vq_fin(const float* __restrict__ loss_sum,
                       float* __restrict__ out_losses) {
  float m = loss_sum[0] / 8388608.0f;
  out_losses[0] = m;
  out_losses[1] = m;
}

extern "C" void kernel_launch(void* const* d_in, const int* in_sizes, int n_in,
                              void* d_out, int out_size, void* d_ws, size_t ws_size,
                              hipStream_t stream) {
  const float* x = (const float*)d_in[0];
  const float* V = (const float*)d_in[1];
  float* out = (float*)d_out;
  float* outq    = out;
  float* outloss = out + 8388608;
  float* outidx  = out + 8388610;

  float* ws_vv  = (float*)d_ws;                          // 16 KB
  float* ws_sum = ws_vv + K_NUM;                         // 4 B
  _Float16* ws_vtb = (_Float16*)((char*)d_ws + 163840);  // 2 MB
  float* ws_vt = (float*)((char*)d_ws + 163840 + 2097152);  // 4 MB
  const int have_vt = (ws_size >= (size_t)(163840 + 2097152 + 4194304));
  float* vt_arg = have_vt ? ws_vt : (float*)nullptr;

  hipMemsetAsync(ws_sum, 0, sizeof(float), stream);
  vq_vv    <<<K_NUM / 256, 256, 0, stream>>>(V, ws_vv);
  vq_prep  <<<256, 256, 0, stream>>>(V, ws_vtb, ws_vt, have_vt);
  vq_screen<<<N_ROWS / 64, 512, 0, stream>>>(x, V, ws_vtb, ws_vv, vt_arg, outidx);
  if (have_vt)
    vq_gather_vt<<<(N_ROWS * (D_DIM / 4)) / 256, 256, 0, stream>>>(
        x, ws_vt, outidx, outq, ws_sum);
  else
    vq_gather<<<(N_ROWS * (D_DIM / 4)) / 256, 256, 0, stream>>>(
        x, V, outidx, outq, ws_sum);
  vq_fin   <<<1, 1, 0, stream>>>(ws_sum, outloss);
}

// Round 6
// 196.744 us; speedup vs baseline: 2.5749x; 1.4718x over previous
//
#include <hip/hip_runtime.h>
#include <math.h>

#define D_DIM 256
#define K_NUM 4096
#define N_ROWS 32768
#define QCAP 3072
#define MARGIN 0.02f

typedef _Float16 half8 __attribute__((ext_vector_type(8)));
typedef float floatx4 __attribute__((ext_vector_type(4)));

// ---------------- vv[k] = sum_d V[d][k]^2 (r1-proven exact order) ------------
__global__ __launch_bounds__(256) void vq_vv(const float* __restrict__ V,
                                             float* __restrict__ vv) {
  int k = blockIdx.x * 256 + threadIdx.x;
  float acc = 0.0f;
  for (int d = 0; d < D_DIM; ++d) {
    float v = V[(size_t)d * K_NUM + k];
    acc = __fadd_rn(acc, __fmul_rn(v, v));
  }
  vv[k] = acc;
}

// ---- V quadrant transpose: 256 blocks of (64 cols x 64 d) -> vtb f16, vt f32
__global__ __launch_bounds__(256) void vq_prep(const float* __restrict__ V,
                                               _Float16* __restrict__ vtb,
                                               float* __restrict__ vt,
                                               int write_vt) {
  __shared__ float tile[64][64];      // [d_local][col_local] 16 KB
  const int col0 = (blockIdx.x & 63) * 64;
  const int d0 = (blockIdx.x >> 6) * 64;
  const int cq = threadIdx.x >> 6;    // 0..3
  const int cl = threadIdx.x & 63;
#pragma unroll
  for (int it = 0; it < 16; ++it) {
    int d = it * 4 + cq;
    tile[d][cl] = V[(size_t)(d0 + d) * K_NUM + col0 + cl];
  }
  __syncthreads();
#pragma unroll
  for (int qq = 0; qq < 2; ++qq) {
    int q = cq * 2 + qq;              // 0..7 local d-chunk
    half8 h;
#pragma unroll
    for (int j = 0; j < 8; ++j) h[j] = (_Float16)tile[q * 8 + j][cl];
    *(half8*)(vtb + ((size_t)(d0 / 8 + q) * K_NUM + col0 + cl) * 8) = h;
  }
  if (write_vt) {
#pragma unroll
    for (int j = 0; j < 4; ++j) {
      int d = cq * 16 + j * 4;
      float4 f;
      f.x = tile[d + 0][cl]; f.y = tile[d + 1][cl];
      f.z = tile[d + 2][cl]; f.w = tile[d + 3][cl];
      *(float4*)(vt + (size_t)(col0 + cl) * D_DIM + d0 + d) = f;
    }
  }
}

// ---------------- fp16 MFMA screen: pass0 threshold + single collect sweep ---
struct alignas(16) ScreenShared {
  _Float16 a[64 * 256];    // 32 KB, low-bit XOR-swizzled
  float vvs[K_NUM];        // 16 KB
  float xxs[64];
  float wmin[8][64];       // 2 KB
  float thr[64];
  unsigned long long best[64];   // (score_bits<<32)|col per row
  unsigned qbuf[QCAP];     // 12 KB
  int qn;
};

__device__ __forceinline__ void vq_push(ScreenShared& sh, int r, int col) {
  int u = atomicAdd(&sh.qn, 1);
  if (u < QCAP) sh.qbuf[u] = ((unsigned)r << 12) | (unsigned)col;
}

// MODE 0: fold cell mins into tb[16].  MODE 1: collect cols with s <= tb.
// ks-pipelined: prefetch ks+1's A (LDS) and B (L2) fragments during ks's MFMAs.
template <int MODE>
__device__ __forceinline__ void vq_cell(ScreenShared& sh,
                                        const _Float16* __restrict__ vtb,
                                        float* tb, int w, int l, int c) {
  const int g = l >> 4, ln = l & 15;
  const int cb = w * 512 + c * 32;
  const float vv0 = sh.vvs[cb + ln];
  const float vv1 = sh.vvs[cb + 16 + ln];

  // A half-offset: (ln<<8) ^ (ch<<3), ch = (ks<<2) ^ g ^ (ln&7)
  const int abase = (ln << 8) ^ ((g ^ (ln & 7)) << 3);
  const char* bp = (const char*)vtb + (((size_t)g * K_NUM + cb + ln) << 4);

  floatx4 acc[4][2];
#pragma unroll
  for (int rf = 0; rf < 4; ++rf)
#pragma unroll
    for (int cf = 0; cf < 2; ++cf) acc[rf][cf] = {0.f, 0.f, 0.f, 0.f};

  half8 afb[2][4], bfb[2][2];
  // prologue: ks = 0 fragments
  bfb[0][0] = *(const half8*)bp;
  bfb[0][1] = *(const half8*)(bp + 256);
#pragma unroll
  for (int rf = 0; rf < 4; ++rf)
    afb[0][rf] = *(const half8*)(sh.a + abase + rf * 4096);

#pragma unroll
  for (int ks = 0; ks < 8; ++ks) {
    const int cur = ks & 1, nxt = cur ^ 1;   // compile-time (full unroll)
    if (ks < 7) {
      const int koff = (ks + 1) * 262144;    // 4*K_NUM*16 bytes per k-step
      bfb[nxt][0] = *(const half8*)(bp + koff);
      bfb[nxt][1] = *(const half8*)(bp + koff + 256);
      const int aoff = abase ^ ((ks + 1) << 5);
#pragma unroll
      for (int rf = 0; rf < 4; ++rf)
        afb[nxt][rf] = *(const half8*)(sh.a + aoff + rf * 4096);
    }
#pragma unroll
    for (int rf = 0; rf < 4; ++rf)
#pragma unroll
      for (int cf = 0; cf < 2; ++cf)
        acc[rf][cf] = __builtin_amdgcn_mfma_f32_16x16x32_f16(
            afb[cur][rf], bfb[cur][cf], acc[rf][cf], 0, 0, 0);
  }

#pragma unroll
  for (int rf = 0; rf < 4; ++rf) {
#pragma unroll
    for (int reg = 0; reg < 4; ++reg) {
      float s0v = fmaf(-2.0f, acc[rf][0][reg], vv0);
      float s1v = fmaf(-2.0f, acc[rf][1][reg], vv1);
      float m = fminf(s0v, s1v);
      if (MODE == 0) {
        tb[rf * 4 + reg] = fminf(tb[rf * 4 + reg], m);
      } else {
        float thr = tb[rf * 4 + reg];
        if (m <= thr) {                  // rare: exec-masked push
          const int r = rf * 16 + g * 4 + reg;
          if (s0v <= thr) vq_push(sh, r, cb + ln);
          if (s1v <= thr) vq_push(sh, r, cb + 16 + ln);
        }
      }
    }
  }
}

__global__ __launch_bounds__(512, 4) void vq_screen(
    const float* __restrict__ X, const float* __restrict__ V,
    const _Float16* __restrict__ vtb, const float* __restrict__ vvp,
    const float* __restrict__ vt, float* __restrict__ idx_out,
    float* __restrict__ outq, float* __restrict__ loss_sum) {
  __shared__ ScreenShared sh;
  const int tid = threadIdx.x;
  const int w = tid >> 6, l = tid & 63;
  const int row0 = blockIdx.x * 64;

  // stage A: f32 -> f16, low-bit XOR-swizzled
#pragma unroll
  for (int it = 0; it < 4; ++it) {
    int idx = it * 512 + tid;
    int r = idx >> 5, s = idx & 31;
    const float* xp = X + (size_t)(row0 + r) * D_DIM + s * 8;
    float4 v0 = *(const float4*)xp, v1 = *(const float4*)(xp + 4);
    half8 h;
    h[0] = (_Float16)v0.x; h[1] = (_Float16)v0.y;
    h[2] = (_Float16)v0.z; h[3] = (_Float16)v0.w;
    h[4] = (_Float16)v1.x; h[5] = (_Float16)v1.y;
    h[6] = (_Float16)v1.z; h[7] = (_Float16)v1.w;
    int slot = (r << 5) | (s ^ (r & 7));
    *(half8*)&sh.a[slot * 8] = h;
  }
#pragma unroll
  for (int it = 0; it < 8; ++it) sh.vvs[it * 512 + tid] = vvp[it * 512 + tid];

  // exact numpy-pairwise ||x||^2, wave-parallel: 16 lanes per row.
  // lane j of 8-group owns accumulator r[j] (16 sequential adds), then the
  // combine tree ((r0+r1)+(r2+r3))+((r4+r5)+(r6+r7)) via shfl_xor (IEEE add
  // is commutative -> bit-identical to np_pw128), halves joined low+high.
  {
    const int grp = tid >> 4;            // 0..31, handles rows 2*grp, 2*grp+1
    const int half = (l >> 3) & 1, j = l & 7;
#pragma unroll
    for (int rr = 0; rr < 2; ++rr) {
      const int r = grp * 2 + rr;
      const float* p = X + (size_t)(row0 + r) * D_DIM + half * 128 + j;
      float v = p[0];
      float acc = __fmul_rn(v, v);
#pragma unroll
      for (int i = 1; i < 16; ++i) {
        v = p[i * 8];
        acc = __fadd_rn(acc, __fmul_rn(v, v));
      }
      acc = __fadd_rn(acc, __shfl_xor(acc, 1));
      acc = __fadd_rn(acc, __shfl_xor(acc, 2));
      acc = __fadd_rn(acc, __shfl_xor(acc, 4));
      acc = __fadd_rn(acc, __shfl_xor(acc, 8));   // low half + high half
      if ((l & 15) == 0) sh.xxs[r] = acc;
    }
  }
  if (tid < 64) sh.best[tid] = 0xFFFFFFFFFFFFFFFFull;
  if (tid == 0) sh.qn = 0;
  __syncthreads();

  float tb[16];
#pragma unroll
  for (int i = 0; i < 16; ++i) tb[i] = INFINITY;

  // pass0: subsampled threshold (c-iters 0 and 8 -> 512 cols blockwide)
  vq_cell<0>(sh, vtb, tb, w, l, 0);
  vq_cell<0>(sh, vtb, tb, w, l, 8);

#pragma unroll
  for (int i = 0; i < 16; ++i) {
#pragma unroll
    for (int off = 1; off <= 8; off <<= 1)
      tb[i] = fminf(tb[i], __shfl_xor(tb[i], off));
  }
  {
    const int g = l >> 4, ln = l & 15;
    if (ln == 0) {
#pragma unroll
      for (int rf = 0; rf < 4; ++rf)
#pragma unroll
        for (int reg = 0; reg < 4; ++reg)
          sh.wmin[w][rf * 16 + g * 4 + reg] = tb[rf * 4 + reg];
    }
  }
  __syncthreads();
  if (tid < 64) {
    float m = sh.wmin[0][tid];
#pragma unroll
    for (int j = 1; j < 8; ++j) m = fminf(m, sh.wmin[j][tid]);
    sh.thr[tid] = m + MARGIN;
  }
  __syncthreads();
  {
    const int g = l >> 4;
#pragma unroll
    for (int rf = 0; rf < 4; ++rf)
#pragma unroll
      for (int reg = 0; reg < 4; ++reg)
        tb[rf * 4 + reg] = sh.thr[rf * 16 + g * 4 + reg];
  }

  // single full sweep, fixed threshold, collect candidates
  for (int c = 0; c < 16; ++c) vq_cell<1>(sh, vtb, tb, w, l, c);
  __syncthreads();

  // exact fp32 rescore (same fma/shfl order as r2-r5-proven rescore)
  const int nq = min(sh.qn, QCAP);
  for (int i = w; i < nq; i += 8) {
    unsigned e = sh.qbuf[i];
    int r = (int)(e >> 12), col = (int)(e & 4095);
    float4 xv = *(const float4*)(X + (size_t)(row0 + r) * D_DIM + l * 4);
    float p = 0.f;
    if (vt) {
      float4 qv = *(const float4*)(vt + (size_t)col * D_DIM + l * 4);
      p = fmaf(xv.x, qv.x, p);
      p = fmaf(xv.y, qv.y, p);
      p = fmaf(xv.z, qv.z, p);
      p = fmaf(xv.w, qv.w, p);
    } else {
      const float* vp = V + col;
      p = fmaf(xv.x, vp[(size_t)(l * 4 + 0) * K_NUM], p);
      p = fmaf(xv.y, vp[(size_t)(l * 4 + 1) * K_NUM], p);
      p = fmaf(xv.z, vp[(size_t)(l * 4 + 2) * K_NUM], p);
      p = fmaf(xv.w, vp[(size_t)(l * 4 + 3) * K_NUM], p);
    }
#pragma unroll
    for (int off = 1; off < 64; off <<= 1) p += __shfl_xor(p, off);
    if (l == 0) {
      float s = __fadd_rn(__fsub_rn(sh.xxs[r], __fmul_rn(2.0f, p)),
                          sh.vvs[col]);
      unsigned long long key =
          ((unsigned long long)__float_as_uint(s) << 32) | (unsigned)col;
      atomicMin(&sh.best[r], key);
    }
  }
  __syncthreads();

  if (tid < 64)
    idx_out[row0 + tid] = (float)(unsigned)(sh.best[tid] & 0xFFFFFFFFu);

  // ---- fused gather + STE + loss (per-element ops identical to r2-r5) ------
  float lsum = 0.f;
#pragma unroll
  for (int it = 0; it < 8; ++it) {
    int t = it * 512 + tid;            // float4 units over 64 rows x 64
    int rloc = t >> 6;
    int c4 = (t & 63) << 2;
    int bi = (int)(unsigned)(sh.best[rloc] & 0xFFFFFFFFu);
    float4 xv = *(const float4*)(X + (size_t)(row0 + rloc) * D_DIM + c4);
    float4 qv;
    if (vt) {
      qv = *(const float4*)(vt + (size_t)bi * D_DIM + c4);
    } else {
      qv.x = V[(size_t)(c4 + 0) * K_NUM + bi];
      qv.y = V[(size_t)(c4 + 1) * K_NUM + bi];
      qv.z = V[(size_t)(c4 + 2) * K_NUM + bi];
      qv.w = V[(size_t)(c4 + 3) * K_NUM + bi];
    }
    float4 o;
    o.x = __fadd_rn(xv.x, __fsub_rn(qv.x, xv.x));
    o.y = __fadd_rn(xv.y, __fsub_rn(qv.y, xv.y));
    o.z = __fadd_rn(xv.z, __fsub_rn(qv.z, xv.z));
    o.w = __fadd_rn(xv.w, __fsub_rn(qv.w, xv.w));
    *(float4*)(outq + (size_t)(row0 + rloc) * D_DIM + c4) = o;
    float d0 = __fsub_rn(xv.x, qv.x), d1 = __fsub_rn(xv.y, qv.y);
    float d2 = __fsub_rn(xv.z, qv.z), d3 = __fsub_rn(xv.w, qv.w);
    lsum += d0 * d0 + d1 * d1 + d2 * d2 + d3 * d3;
  }
#pragma unroll
  for (int off = 1; off < 64; off <<= 1) lsum += __shfl_xor(lsum, off);
  __syncthreads();                     // qbuf no longer needed -> reuse as red
  float* red = (float*)sh.qbuf;
  if (l == 0) red[w] = lsum;
  __syncthreads();
  if (tid == 0) {
    float s = red[0];
#pragma unroll
    for (int j = 1; j < 8; ++j) s += red[j];
    atomicAdd(loss_sum, s);
  }
}

__global__ void vq_fin(const float* __restrict__ loss_sum,
                       float* __restrict__ out_losses) {
  float m = loss_sum[0] / 8388608.0f;
  out_losses[0] = m;
  out_losses[1] = m;
}

extern "C" void kernel_launch(void* const* d_in, const int* in_sizes, int n_in,
                              void* d_out, int out_size, void* d_ws, size_t ws_size,
                              hipStream_t stream) {
  const float* x = (const float*)d_in[0];
  const float* V = (const float*)d_in[1];
  float* out = (float*)d_out;
  float* outq    = out;
  float* outloss = out + 8388608;
  float* outidx  = out + 8388610;

  float* ws_vv  = (float*)d_ws;                          // 16 KB
  float* ws_sum = ws_vv + K_NUM;                         // 4 B
  _Float16* ws_vtb = (_Float16*)((char*)d_ws + 163840);  // 2 MB
  float* ws_vt = (float*)((char*)d_ws + 163840 + 2097152);  // 4 MB
  const int have_vt = (ws_size >= (size_t)(163840 + 2097152 + 4194304));
  float* vt_arg = have_vt ? ws_vt : (float*)nullptr;

  hipMemsetAsync(ws_sum, 0, sizeof(float), stream);
  vq_vv    <<<K_NUM / 256, 256, 0, stream>>>(V, ws_vv);
  vq_prep  <<<256, 256, 0, stream>>>(V, ws_vtb, ws_vt, have_vt);
  vq_screen<<<N_ROWS / 64, 512, 0, stream>>>(x, V, ws_vtb, ws_vv, vt_arg,
                                             outidx, outq, ws_sum);
  vq_fin   <<<1, 1, 0, stream>>>(ws_sum, outloss);
}